// Round 5
// baseline (140.731 us; speedup 1.0000x reference)
//
#include <hip/hip_runtime.h>

#define NB 128      // batch
#define NT 4096     // T
#define DKD 16      // d_k == d_q
#define DW 32       // d_w
#define BLK 1024    // one block per batch: 1024 threads x 4 t/thread = 4096
#define PT 4

__device__ __forceinline__ float fast_tanh(float x) {
    // tanh(x) = 1 - 2/(e^{2x}+1); exact at +/-inf limits, ~1 ulp rcp error.
    float e = __expf(2.0f * x);
    return 1.0f - 2.0f * __builtin_amdgcn_rcpf(e + 1.0f);
}

// ONE kernel, ONE block per batch (128 blocks x 1024 threads), zero fences,
// zero workspace, zero cross-block communication.
//   Rounds 1-2: fused-with-fences loses 40-60us to L2 writeback/invalidate.
//   Rounds 0/3/4: fence-free 2-kernel pair is stuck at ~35us regardless of
//   occupancy — second dispatch + 4.2MB p round-trip + per-t-redundant LDS
//   (W2 re-read and 17-value butterfly per single t at PT=1).
// This version: the whole batch row (T=4096) lives in one block, so the
// softmax denominator and context reduce IN-BLOCK via LDS; p stays in
// registers across the reduction and is written normalized exactly once.
// W2 LDS reads amortize over PT=4 t's; value loads issue as one 16-dwordx4
// burst whose latency is hidden by 16 waves/CU of TLP.
__global__ __launch_bounds__(BLK, 1) void aa_fused(
    const float* __restrict__ query, const float* __restrict__ key,
    const float* __restrict__ value, const float* __restrict__ W1,
    const float* __restrict__ W2, const float* __restrict__ bias,
    const float* __restrict__ v_w, const float* __restrict__ v_b,
    float* __restrict__ out)            // [0,2048): context; [2048,..): attn
{
    const int b   = blockIdx.x;
    const int tid = threadIdx.x;

    __shared__ float s_w2[DW * DKD];     // [w][d] row-major (2 KB)
    __shared__ float s_cv[DW * 2];       // packed (comb, vw) pairs -> b64 read
    __shared__ float s_red[16 * 17];     // per-wave partials: 16 ctx + l
    __shared__ float s_fin[17];          // final: 16 ctx sums + L

    // Preamble: stage W2 (128 float4) and compute q_proj + bias (32 lanes).
    if (tid < 128)
        reinterpret_cast<float4*>(s_w2)[tid] = reinterpret_cast<const float4*>(W2)[tid];
    if (tid >= 128 && tid < 128 + DW) {
        const int w = tid - 128;
        float acc = bias[0];
        const float* q  = query + b * DKD;
        const float* w1 = W1 + w * DKD;
        #pragma unroll
        for (int d = 0; d < DKD; ++d) acc = fmaf(q[d], w1[d], acc);
        s_cv[2 * w]     = acc;       // comb = q_proj[w] + bias
        s_cv[2 * w + 1] = v_w[w];    // vw
    }
    __syncthreads();

    const float vb = v_b[0];
    // Thread handles PT=4 consecutive t's: 256 B contiguous per lane per
    // array; the wave covers a contiguous 16 KB slab (proven pattern).
    const size_t tbase = (size_t)b * NT + (size_t)tid * PT;
    const float4* kp = reinterpret_cast<const float4*>(key)   + tbase * 4;
    const float4* vp = reinterpret_cast<const float4*>(value) + tbase * 4;

    // Key tile in registers (16 dwordx4 in flight).
    float4 k0[PT], k1[PT], k2[PT], k3[PT];
    #pragma unroll
    for (int j = 0; j < PT; ++j) {
        k0[j] = kp[4*j + 0]; k1[j] = kp[4*j + 1];
        k2[j] = kp[4*j + 2]; k3[j] = kp[4*j + 3];
    }

    float sc[PT];
    #pragma unroll
    for (int j = 0; j < PT; ++j) sc[j] = vb;

    // w-outer, t-inner: 5 DS reads per w serve 4 t's (68 FMA) — LDS pipe
    // stays well under the FMA pipe. All reads wave-uniform -> broadcast,
    // conflict-free.
    #pragma unroll 4
    for (int w = 0; w < DW; ++w) {
        const float4* wr = reinterpret_cast<const float4*>(s_w2 + w * DKD);
        const float4 w0 = wr[0], w1 = wr[1], w2 = wr[2], w3 = wr[3];
        const float2 cv = *reinterpret_cast<const float2*>(s_cv + 2 * w);
        #pragma unroll
        for (int j = 0; j < PT; ++j) {
            float h = cv.x;
            h = fmaf(k0[j].x, w0.x, h); h = fmaf(k0[j].y, w0.y, h);
            h = fmaf(k0[j].z, w0.z, h); h = fmaf(k0[j].w, w0.w, h);
            h = fmaf(k1[j].x, w1.x, h); h = fmaf(k1[j].y, w1.y, h);
            h = fmaf(k1[j].z, w1.z, h); h = fmaf(k1[j].w, w1.w, h);
            h = fmaf(k2[j].x, w2.x, h); h = fmaf(k2[j].y, w2.y, h);
            h = fmaf(k2[j].z, w2.z, h); h = fmaf(k2[j].w, w2.w, h);
            h = fmaf(k3[j].x, w3.x, h); h = fmaf(k3[j].y, w3.y, h);
            h = fmaf(k3[j].z, w3.z, h); h = fmaf(k3[j].w, w3.w, h);
            sc[j] = fmaf(fast_tanh(h), cv.y, sc[j]);
        }
    }

    // p = exp(score) — |score| <= ||v_w||_1 + |v_b| ~ 2.6 (tanh bounded), so
    // no max-subtract needed. Value tile loads issue here as one burst; the
    // within-wave latency is hidden by 15 other waves on the CU.
    float l = 0.0f;
    float ctx[16];
    #pragma unroll
    for (int d = 0; d < 16; ++d) ctx[d] = 0.0f;

    float p[PT];
    #pragma unroll
    for (int j = 0; j < PT; ++j) {
        p[j] = __expf(sc[j]);
        l += p[j];
        const float4 v0 = vp[4*j + 0], v1 = vp[4*j + 1];
        const float4 v2 = vp[4*j + 2], v3 = vp[4*j + 3];
        ctx[ 0] = fmaf(p[j], v0.x, ctx[ 0]); ctx[ 1] = fmaf(p[j], v0.y, ctx[ 1]);
        ctx[ 2] = fmaf(p[j], v0.z, ctx[ 2]); ctx[ 3] = fmaf(p[j], v0.w, ctx[ 3]);
        ctx[ 4] = fmaf(p[j], v1.x, ctx[ 4]); ctx[ 5] = fmaf(p[j], v1.y, ctx[ 5]);
        ctx[ 6] = fmaf(p[j], v1.z, ctx[ 6]); ctx[ 7] = fmaf(p[j], v1.w, ctx[ 7]);
        ctx[ 8] = fmaf(p[j], v2.x, ctx[ 8]); ctx[ 9] = fmaf(p[j], v2.y, ctx[ 9]);
        ctx[10] = fmaf(p[j], v2.z, ctx[10]); ctx[11] = fmaf(p[j], v2.w, ctx[11]);
        ctx[12] = fmaf(p[j], v3.x, ctx[12]); ctx[13] = fmaf(p[j], v3.y, ctx[13]);
        ctx[14] = fmaf(p[j], v3.z, ctx[14]); ctx[15] = fmaf(p[j], v3.w, ctx[15]);
    }

    // In-block reduction: wave butterfly, then 16 waves via LDS.
    #pragma unroll
    for (int o = 32; o > 0; o >>= 1) l += __shfl_xor(l, o);
    #pragma unroll
    for (int d = 0; d < 16; ++d) {
        #pragma unroll
        for (int o = 32; o > 0; o >>= 1) ctx[d] += __shfl_xor(ctx[d], o);
    }
    const int wave = tid >> 6;
    const int lane = tid & 63;
    if (lane == 0) {
        #pragma unroll
        for (int d = 0; d < 16; ++d) s_red[wave * 17 + d] = ctx[d];
        s_red[wave * 17 + 16] = l;
    }
    __syncthreads();
    if (tid < 17) {
        float s = 0.0f;
        #pragma unroll
        for (int wv = 0; wv < 16; ++wv) s += s_red[wv * 17 + tid];
        s_fin[tid] = s;
    }
    __syncthreads();

    const float inv = 1.0f / s_fin[16];   // broadcast LDS read, precise div

    // Write normalized attn exactly once: float4 of 4 consecutive t's.
    reinterpret_cast<float4*>(out + NB * DKD + (size_t)b * NT)[tid] =
        make_float4(p[0] * inv, p[1] * inv, p[2] * inv, p[3] * inv);

    // Context output.
    if (tid < DKD)
        out[b * DKD + tid] = s_fin[tid] * inv;
}

extern "C" void kernel_launch(void* const* d_in, const int* in_sizes, int n_in,
                              void* d_out, int out_size, void* d_ws, size_t ws_size,
                              hipStream_t stream) {
    const float* query = (const float*)d_in[0];
    const float* key   = (const float*)d_in[1];
    const float* value = (const float*)d_in[2];
    const float* W1    = (const float*)d_in[3];
    const float* W2    = (const float*)d_in[4];
    const float* bias  = (const float*)d_in[5];
    const float* v_w   = (const float*)d_in[6];
    const float* v_b   = (const float*)d_in[7];
    float* out = (float*)d_out;

    aa_fused<<<NB, BLK, 0, stream>>>(
        query, key, value, W1, W2, bias, v_w, v_b, out);
}

// Round 6
// 121.951 us; speedup vs baseline: 1.1540x; 1.1540x over previous
//
#include <hip/hip_runtime.h>

#define NB 128      // batch
#define NT 4096     // T
#define DKD 16      // d_k == d_q
#define DW 32       // d_w
#define CHUNKS 4    // T chunks: 512 blocks, 2 blocks/CU, 8 waves/CU
#define TC 1024     // NT / CHUNKS
#define BLK 256
#define PT 4        // t-values per thread: TC / BLK

__device__ __forceinline__ float fast_tanh(float x) {
    // tanh(x) = 1 - 2/(e^{2x}+1); exact at +/-inf limits, ~1 ulp rcp error.
    float e = __expf(2.0f * x);
    return 1.0f - 2.0f * __builtin_amdgcn_rcpf(e + 1.0f);
}

// Two fence-free kernels (rounds 1-2: fences lose 40-60us; round 5: one
// block/batch idles half the chip). Round-5 analysis: the stuck ~30us pair
// was DS-pipe-bound — 160 ds_read/wave of W2 (~12cy each, per-CU pipe) +
// the 17x6 shuffle butterfly exceeded the 11us HBM share, with VALUBusy
// 12-18% as the symptom.
// This round: W2 is read UNIFORMLY from global inside the w-loop — the
// address depends only on the loop counter, so the compiler scalarizes it
// to s_load through the scalar cache (SMEM), freeing the DS pipe entirely
// and deleting the 2KB staging preamble + its barrier. Only the per-block
// (comb, vw) float2 table stays in LDS (32 ds_read_b64/wave). PT=4 keeps
// per-wave fixed costs (butterfly) amortized over 4 t's.
__global__ __launch_bounds__(BLK, 2) void aa_score(
    const float* __restrict__ query, const float* __restrict__ key,
    const float* __restrict__ value, const float* __restrict__ W1,
    const float* __restrict__ W2, const float* __restrict__ bias,
    const float* __restrict__ v_w, const float* __restrict__ v_b,
    float* __restrict__ attn,      // out + 2048: unnormalized p written here
    float* __restrict__ ws_l,      // [NB*CHUNKS]
    float* __restrict__ ws_ctx)    // [NB*CHUNKS*16]
{
    const int b   = blockIdx.x >> 2;            // blockIdx / CHUNKS
    const int c   = blockIdx.x & (CHUNKS - 1);
    const int tid = threadIdx.x;

    __shared__ float2 s_cv[DW];        // (comb = q_proj + bias, vw) pairs
    __shared__ float s_rctx[4 * 16];   // per-wave partial ctx
    __shared__ float s_rl[4];

    // Preamble: 32 lanes compute q_proj + bias and pack (comb, vw).
    if (tid < DW) {
        float acc = bias[0];
        const float* q  = query + b * DKD;
        const float* wr = W1 + tid * DKD;
        #pragma unroll
        for (int d = 0; d < DKD; ++d) acc = fmaf(q[d], wr[d], acc);
        s_cv[tid] = make_float2(acc, v_w[tid]);
    }
    __syncthreads();

    const float vb = v_b[0];
    // Thread handles PT=4 consecutive t's: 256 B contiguous per lane per
    // array; the wave covers a contiguous 16 KB slab.
    const size_t tbase = (size_t)b * NT + (size_t)c * TC + (size_t)tid * PT;
    const float4* kp = reinterpret_cast<const float4*>(key)   + tbase * 4;
    const float4* vp = reinterpret_cast<const float4*>(value) + tbase * 4;

    // Prefetch BOTH key and value tiles: 32 global_load_dwordx4 in flight;
    // HBM streams both arrays while the score loop runs.
    float4 k0[PT], k1[PT], k2[PT], k3[PT];
    float4 v0[PT], v1[PT], v2[PT], v3[PT];
    #pragma unroll
    for (int j = 0; j < PT; ++j) {
        k0[j] = kp[4*j + 0]; k1[j] = kp[4*j + 1];
        k2[j] = kp[4*j + 2]; k3[j] = kp[4*j + 3];
    }
    #pragma unroll
    for (int j = 0; j < PT; ++j) {
        v0[j] = vp[4*j + 0]; v1[j] = vp[4*j + 1];
        v2[j] = vp[4*j + 2]; v3[j] = vp[4*j + 3];
    }

    float sc[PT];
    #pragma unroll
    for (int j = 0; j < PT; ++j) sc[j] = vb;

    // w-outer, t-inner. W2 row address is wave-uniform (loop-counter only):
    // compiler emits s_load_dwordx4 via the scalar cache — zero DS traffic.
    // v_fma takes the SGPR operand directly (1 SGPR src per VALU is legal).
    #pragma unroll 4
    for (int w = 0; w < DW; ++w) {
        const float4* wrow = reinterpret_cast<const float4*>(W2 + w * DKD);
        const float4 u0 = wrow[0], u1 = wrow[1], u2 = wrow[2], u3 = wrow[3];
        const float2 cv = s_cv[w];     // ds_read_b64, wave-broadcast
        #pragma unroll
        for (int j = 0; j < PT; ++j) {
            float h = cv.x;
            h = fmaf(k0[j].x, u0.x, h); h = fmaf(k0[j].y, u0.y, h);
            h = fmaf(k0[j].z, u0.z, h); h = fmaf(k0[j].w, u0.w, h);
            h = fmaf(k1[j].x, u1.x, h); h = fmaf(k1[j].y, u1.y, h);
            h = fmaf(k1[j].z, u1.z, h); h = fmaf(k1[j].w, u1.w, h);
            h = fmaf(k2[j].x, u2.x, h); h = fmaf(k2[j].y, u2.y, h);
            h = fmaf(k2[j].z, u2.z, h); h = fmaf(k2[j].w, u2.w, h);
            h = fmaf(k3[j].x, u3.x, h); h = fmaf(k3[j].y, u3.y, h);
            h = fmaf(k3[j].z, u3.z, h); h = fmaf(k3[j].w, u3.w, h);
            sc[j] = fmaf(fast_tanh(h), cv.y, sc[j]);
        }
    }

    // p = exp(score) — |score| <= ||v_w||_1 + |v_b| ~ 2.6 (tanh bounded), so
    // no max-subtract needed. value already in registers.
    float l = 0.0f;
    float ctx[16];
    #pragma unroll
    for (int d = 0; d < 16; ++d) ctx[d] = 0.0f;

    float p[PT];
    #pragma unroll
    for (int j = 0; j < PT; ++j) {
        p[j] = __expf(sc[j]);
        l += p[j];
        ctx[ 0] = fmaf(p[j], v0[j].x, ctx[ 0]); ctx[ 1] = fmaf(p[j], v0[j].y, ctx[ 1]);
        ctx[ 2] = fmaf(p[j], v0[j].z, ctx[ 2]); ctx[ 3] = fmaf(p[j], v0[j].w, ctx[ 3]);
        ctx[ 4] = fmaf(p[j], v1[j].x, ctx[ 4]); ctx[ 5] = fmaf(p[j], v1[j].y, ctx[ 5]);
        ctx[ 6] = fmaf(p[j], v1[j].z, ctx[ 6]); ctx[ 7] = fmaf(p[j], v1[j].w, ctx[ 7]);
        ctx[ 8] = fmaf(p[j], v2[j].x, ctx[ 8]); ctx[ 9] = fmaf(p[j], v2[j].y, ctx[ 9]);
        ctx[10] = fmaf(p[j], v2[j].z, ctx[10]); ctx[11] = fmaf(p[j], v2[j].w, ctx[11]);
        ctx[12] = fmaf(p[j], v3[j].x, ctx[12]); ctx[13] = fmaf(p[j], v3[j].y, ctx[13]);
        ctx[14] = fmaf(p[j], v3[j].z, ctx[14]); ctx[15] = fmaf(p[j], v3[j].w, ctx[15]);
    }

    // Write unnormalized p (kernel 2 normalizes in place): 16 B/lane,
    // wave-contiguous 1 KB — coalesced.
    reinterpret_cast<float4*>(attn + (size_t)b * NT + (size_t)c * TC)[tid] =
        make_float4(p[0], p[1], p[2], p[3]);

    // Block reduction: wave shuffle-reduce, then 4 waves via LDS.
    #pragma unroll
    for (int o = 32; o > 0; o >>= 1) l += __shfl_xor(l, o);
    #pragma unroll
    for (int d = 0; d < 16; ++d) {
        #pragma unroll
        for (int o = 32; o > 0; o >>= 1) ctx[d] += __shfl_xor(ctx[d], o);
    }
    const int wave = tid >> 6;
    const int lane = tid & 63;
    if (lane == 0) {
        s_rl[wave] = l;
        #pragma unroll
        for (int d = 0; d < 16; ++d) s_rctx[wave * 16 + d] = ctx[d];
    }
    __syncthreads();
    const int slot = b * CHUNKS + c;
    if (tid < 16)
        ws_ctx[slot * 16 + tid] =
            s_rctx[tid] + s_rctx[16 + tid] + s_rctx[32 + tid] + s_rctx[48 + tid];
    if (tid == 0)
        ws_l[slot] = s_rl[0] + s_rl[1] + s_rl[2] + s_rl[3];
}

// Kernel 2: normalize attn in place by 1/L and write context. 512 fat blocks
// (float4/thread); L recomputed per block from 4 broadcast (scalar-cache)
// loads — avoids a third kernel.
__global__ __launch_bounds__(BLK) void aa_finish(
    float* __restrict__ out,          // [0,2048) context, [2048,...) attn
    const float* __restrict__ ws_l,
    const float* __restrict__ ws_ctx)
{
    const int b   = blockIdx.x >> 2;            // 4 blocks per batch
    const int q   = blockIdx.x & 3;             // quarter of the row
    const int tid = threadIdx.x;

    float L = 0.0f;
    #pragma unroll
    for (int i = 0; i < CHUNKS; ++i) L += ws_l[b * CHUNKS + i];
    const float inv = 1.0f / L;

    // 4 blocks x 256 threads x float4 = 4096 floats = one batch row.
    float4* ap = reinterpret_cast<float4*>(out + NB * DKD + (size_t)b * NT) +
                 q * BLK + tid;
    float4 p = *ap;
    p.x *= inv; p.y *= inv; p.z *= inv; p.w *= inv;
    *ap = p;

    if (q == 0 && tid < DKD) {
        const float* wc = ws_ctx + b * CHUNKS * 16;
        float s = 0.0f;
        #pragma unroll
        for (int i = 0; i < CHUNKS; ++i) s += wc[i * 16 + tid];
        out[b * DKD + tid] = s * inv;
    }
}

extern "C" void kernel_launch(void* const* d_in, const int* in_sizes, int n_in,
                              void* d_out, int out_size, void* d_ws, size_t ws_size,
                              hipStream_t stream) {
    const float* query = (const float*)d_in[0];
    const float* key   = (const float*)d_in[1];
    const float* value = (const float*)d_in[2];
    const float* W1    = (const float*)d_in[3];
    const float* W2    = (const float*)d_in[4];
    const float* bias  = (const float*)d_in[5];
    const float* v_w   = (const float*)d_in[6];
    const float* v_b   = (const float*)d_in[7];
    float* out = (float*)d_out;

    float* ws_l   = (float*)d_ws;          // NB*CHUNKS floats
    float* ws_ctx = ws_l + NB * CHUNKS;    // NB*CHUNKS*16 floats

    aa_score<<<NB * CHUNKS, BLK, 0, stream>>>(
        query, key, value, W1, W2, bias, v_w, v_b,
        out + NB * DKD, ws_l, ws_ctx);
    aa_finish<<<NB * (NT / 4 / BLK), BLK, 0, stream>>>(out, ws_l, ws_ctx);
}